// Round 4
// baseline (5186.306 us; speedup 1.0000x reference)
//
#include <hip/hip_runtime.h>

typedef _Float16 f16;
typedef _Float16 h2 __attribute__((ext_vector_type(2)));
typedef _Float16 h4 __attribute__((ext_vector_type(4)));
typedef _Float16 h8 __attribute__((ext_vector_type(8)));

#define T127 127

__device__ __forceinline__ float rcp_f(float x) { return __builtin_amdgcn_rcpf(x); }

__device__ __forceinline__ float fdot2(h2 a, h2 b, float c) {
  return __builtin_amdgcn_fdot2(a, b, c, false);
}
__device__ __forceinline__ h2 mk2(f16 a, f16 b) { h2 v; v[0] = a; v[1] = b; return v; }

__device__ __forceinline__ float fast_tanh(float x) {
  x = fminf(fmaxf(x, -12.f), 12.f);
  float e = __expf(2.f * x);
  return (e - 1.f) * rcp_f(e + 1.f);
}
__device__ __forceinline__ float fast_sig(float x) {
  x = fminf(fmaxf(x, -30.f), 30.f);
  return rcp_f(1.f + __expf(-x));
}

// Pack Whh fp32 [1024][256] -> fp16 d_ws layout [32][1024][8]:
// ws[(c*1024 + r)*8 + j] = Whh[r][8c + j]  (lane-coalesced stream reads)
__global__ void pack_whh(const float* __restrict__ Whh, f16* __restrict__ ws) {
  int r = blockIdx.x;     // 0..1023
  int col = threadIdx.x;  // 0..255
  float v = Whh[r * 256 + col];
  int c = col >> 3, j = col & 7;
  ws[((size_t)(c * 1024 + r)) * 8 + j] = (f16)v;
}

// One block per 2 batches; 256 blocks x 1024 threads, 1 block/CU (LDS-bound).
// amdgpu_waves_per_eu(4,4): EXACTLY 4 waves/EU -> 512/4 = 128 VGPR budget.
// (__launch_bounds__(1024,1) and (1024,4) both left the heuristic at 8
// waves/EU -> 64 VGPRs -> w1[] + loop temps spilled to scratch: 7.9 GB
// FETCH + 4.9 GB WRITE of pure spill traffic per launch. Do not regress.)
__global__ __attribute__((amdgpu_flat_work_group_size(1024, 1024), amdgpu_waves_per_eu(4, 4)))
void decoder_kernel(
    const float* __restrict__ enc,    // [512][127][256]
    const float* __restrict__ yhist,  // [512][127]
    const float* __restrict__ Wa1,    // [256][768]  cols: h(0:256) c(256:512) e(512:768)
    const float* __restrict__ ba1,    // [256]
    const float* __restrict__ Wa2,    // [256]
    const float* __restrict__ ba2,    // [1]
    const float* __restrict__ Wih,    // [1024]
    const float* __restrict__ Whh,    // [1024][256] (unused in loop; packed copy in wsW)
    const float* __restrict__ bih,    // [1024]
    const float* __restrict__ bhh,    // [1024]
    const float* __restrict__ Wfc,    // [257]
    const float* __restrict__ bfc,    // [1]
    const float* __restrict__ Wfcf,   // [512]
    const float* __restrict__ bfcf,   // [1]
    const f16* __restrict__ wsW,      // [32][1024][8] packed Whh fp16
    float* __restrict__ outp)         // [512] out ++ [512][127][127] weight
{
  // tE1 row: 4 chunks of 64 elems at offsets g*68 (34 dwords -> bank shift 2/g:
  // conflict-free for the PhaseB b64 pattern; g*64 was 4-way same-bank).
  __shared__ __align__(16) f16 tE1[2][T127][272];   // 138176 B
  __shared__ __align__(16) f16 hch[2][4][136];      // [h;c] fp16, chunk stride 272 B
  __shared__ __align__(16) float s_arr[2][4][68];   // s = tanh(u+b1)
  __shared__ __align__(16) float score_s[2][128];
  __shared__ __align__(16) float p_s[2][128];       // e . Wfc[0:256]
  __shared__ __align__(16) float q_s[2][128];       // e . Wfcf[256:512]
  __shared__ __align__(16) char ovl[9216];          // est [16][288] f16 UNION gact [2][1024] f32
  __shared__ __align__(16) float c_s[2][256];       // exact fp32 cell state
  __shared__ __align__(16) float w2_lds[256];
  __shared__ __align__(16) float yh_s[2][128];
  __shared__ float ytil[2], ctxq_s[2], red[16];

  float* gact = (float*)ovl;
  f16* est = (f16*)ovl;   // est row: chunks at g*72 (36 dwords: conflict-free, 16B-aligned)

  const int L = threadIdx.x;
  const int b0 = blockIdx.x * 2;
  const int k_u = L >> 2;  // output index 0..255 (u / score-pair)
  const int g_u = L & 3;   // quad member: col-chunk selector

  // ---------------- init ----------------
  for (int i = L; i < 1088; i += 1024) ((f16*)hch)[i] = (f16)0.f;
  if (L < 512) ((float*)c_s)[L] = 0.f;
  if (L < 256) {
    w2_lds[L] = Wa2[L];
    int bb = L >> 7, tt = L & 127;
    if (tt < T127) yh_s[bb][tt] = yhist[(size_t)(b0 + bb) * T127 + tt];
  }

  // ---------------- prologue: tE1 = tanh(e.W1e), p, q ----------------
  {
    // quad-split W1e: lane holds 64 cols (32 h2 regs)
    h2 we1[32];
    {
      const float4* wrow = (const float4*)(Wa1 + (size_t)k_u * 768 + 512 + g_u * 64);
#pragma unroll
      for (int i = 0; i < 16; ++i) {
        float4 w = wrow[i];
        we1[2 * i]     = mk2((f16)w.x, (f16)w.y);
        we1[2 * i + 1] = mk2((f16)w.z, (f16)w.w);
      }
    }
    const int prpair = L >> 6;  // wave id = staging pair 0..15
    const int lm = L & 63;
    const int sg = lm >> 4;           // staging chunk 0..3
    const int si = (lm * 4) & 63;     // within-chunk elem

#pragma unroll 1
    for (int tt = 0; tt < 16; ++tt) {
      __syncthreads();
      {  // stage 16 (b,j) rows of e as fp16: pair = bb*8 + j8, j = tt*8+j8
        int bbs = prpair >> 3, j8 = prpair & 7, j = tt * 8 + j8;
        float4 v = make_float4(0.f, 0.f, 0.f, 0.f);
        if (j < T127)
          v = *(const float4*)(enc + (((size_t)(b0 + bbs)) * T127 + j) * 256 + lm * 4);
        h4 hv; hv[0] = (f16)v.x; hv[1] = (f16)v.y; hv[2] = (f16)v.z; hv[3] = (f16)v.w;
        *(h4*)(est + prpair * 288 + sg * 72 + si) = hv;
      }
      __syncthreads();
      // every quad computes all 16 pairs: 64-col partial dot + quad reduce
#pragma unroll 1
      for (int P = 0; P < 16; ++P) {
        int bbs = P >> 3, j8 = P & 7, j = tt * 8 + j8;
        const h8* ep = (const h8*)(est + P * 288 + g_u * 72);
        float a0 = 0.f, a1 = 0.f;
#pragma unroll
        for (int r = 0; r < 8; ++r) {
          h8 e8 = ep[r];
          a0 = fdot2(we1[4 * r + 0], mk2(e8[0], e8[1]), a0);
          a1 = fdot2(we1[4 * r + 1], mk2(e8[2], e8[3]), a1);
          a0 = fdot2(we1[4 * r + 2], mk2(e8[4], e8[5]), a0);
          a1 = fdot2(we1[4 * r + 3], mk2(e8[6], e8[7]), a1);
        }
        float acc = a0 + a1;
        acc += __shfl_xor(acc, 1, 64);
        acc += __shfl_xor(acc, 2, 64);
        if (g_u == 0 && j < T127)
          tE1[bbs][j][(k_u >> 6) * 68 + (k_u & 63)] = (f16)fast_tanh(acc);
      }
      {  // p, q for this wave's pair
        int P = prpair, bbs = P >> 3, j8 = P & 7, j = tt * 8 + j8;
        float4 wp4 = *(const float4*)(Wfc + lm * 4);
        float4 wq4 = *(const float4*)(Wfcf + 256 + lm * 4);
        h4 ev = *(const h4*)(est + P * 288 + sg * 72 + si);
        float pacc = (float)ev[0] * wp4.x + (float)ev[1] * wp4.y + (float)ev[2] * wp4.z + (float)ev[3] * wp4.w;
        float qacc = (float)ev[0] * wq4.x + (float)ev[1] * wq4.y + (float)ev[2] * wq4.z + (float)ev[3] * wq4.w;
#pragma unroll
        for (int s = 32; s; s >>= 1) {
          pacc += __shfl_xor(pacc, s, 64);
          qacc += __shfl_xor(qacc, s, 64);
        }
        if (lm == 0 && j < T127) { p_s[bbs][j] = pacc; q_s[bbs][j] = qacc; }
      }
    }
  }
  __syncthreads();

  // ---------------- persistent registers ----------------
  h2 w1[64];  // Wa1[k_u, g_u*128 : +128] (h|c part), fp16
  {
    const float4* wrow = (const float4*)(Wa1 + (size_t)k_u * 768 + g_u * 128);
#pragma unroll
    for (int i = 0; i < 32; ++i) {
      float4 w = wrow[i];
      w1[2 * i]     = mk2((f16)w.x, (f16)w.y);
      w1[2 * i + 1] = mk2((f16)w.z, (f16)w.w);
    }
  }
  const float b1k = ba1[k_u];
  const float wihn = Wih[L];
  const float biasn = bih[L] + bhh[L];
  const float ba2v = ba2[0];
  const float wfcy = Wfc[256];
  const float bfc0 = bfc[0];
  __syncthreads();

  // ---------------- 127 sequential steps ----------------
#pragma unroll 1
  for (int t = 0; t < T127; ++t) {
    // prefetch first Whh stream chunks (land during u-dots)
    const h8* wp = (const h8*)wsW + L;  // chunk c at wp[c*1024]
    h8 wv0 = wp[0];
    h8 wv1 = wp[1024];

    // ---- Phase A1: u = W1.[h;c] -> s=tanh(u+b1)  (register weights) ----
    float u0a = 0.f, u0b = 0.f, u1a = 0.f, u1b = 0.f;
    {
      const h8* hp = (const h8*)&hch[0][g_u][0];
#pragma unroll
      for (int r = 0; r < 16; ++r) {
        h8 a = hp[r];
        u0a = fdot2(w1[4 * r + 0], mk2(a[0], a[1]), u0a);
        u0b = fdot2(w1[4 * r + 1], mk2(a[2], a[3]), u0b);
        u0a = fdot2(w1[4 * r + 2], mk2(a[4], a[5]), u0a);
        u0b = fdot2(w1[4 * r + 3], mk2(a[6], a[7]), u0b);
      }
      hp = (const h8*)&hch[1][g_u][0];
#pragma unroll
      for (int r = 0; r < 16; ++r) {
        h8 a = hp[r];
        u1a = fdot2(w1[4 * r + 0], mk2(a[0], a[1]), u1a);
        u1b = fdot2(w1[4 * r + 1], mk2(a[2], a[3]), u1b);
        u1a = fdot2(w1[4 * r + 2], mk2(a[4], a[5]), u1a);
        u1b = fdot2(w1[4 * r + 3], mk2(a[6], a[7]), u1b);
      }
    }

    // ---- Phase A2: gh = Whh.h, Whh streamed from L2, 2-deep pipeline ----
    float gh0 = 0.f, gh1 = 0.f;
#pragma unroll 1
    for (int cb = 0; cb < 16; ++cb) {
      int cn0 = (cb < 15) ? (cb * 2 + 2) : 0;  // wrap: harmless dummy load last iter
      int cn1 = (cb < 15) ? (cb * 2 + 3) : 1;
      h8 n0 = wp[cn0 * 1024];
      h8 n1 = wp[cn1 * 1024];
      int c0 = cb * 2, c1 = cb * 2 + 1;
      h8 h00 = *(const h8*)&hch[0][c0 >> 4][(c0 & 15) * 8];
      h8 h10 = *(const h8*)&hch[1][c0 >> 4][(c0 & 15) * 8];
      gh0 = fdot2(mk2(wv0[0], wv0[1]), mk2(h00[0], h00[1]), gh0);
      gh0 = fdot2(mk2(wv0[2], wv0[3]), mk2(h00[2], h00[3]), gh0);
      gh0 = fdot2(mk2(wv0[4], wv0[5]), mk2(h00[4], h00[5]), gh0);
      gh0 = fdot2(mk2(wv0[6], wv0[7]), mk2(h00[6], h00[7]), gh0);
      gh1 = fdot2(mk2(wv0[0], wv0[1]), mk2(h10[0], h10[1]), gh1);
      gh1 = fdot2(mk2(wv0[2], wv0[3]), mk2(h10[2], h10[3]), gh1);
      gh1 = fdot2(mk2(wv0[4], wv0[5]), mk2(h10[4], h10[5]), gh1);
      gh1 = fdot2(mk2(wv0[6], wv0[7]), mk2(h10[6], h10[7]), gh1);
      h8 h01 = *(const h8*)&hch[0][c1 >> 4][(c1 & 15) * 8];
      h8 h11 = *(const h8*)&hch[1][c1 >> 4][(c1 & 15) * 8];
      gh0 = fdot2(mk2(wv1[0], wv1[1]), mk2(h01[0], h01[1]), gh0);
      gh0 = fdot2(mk2(wv1[2], wv1[3]), mk2(h01[2], h01[3]), gh0);
      gh0 = fdot2(mk2(wv1[4], wv1[5]), mk2(h01[4], h01[5]), gh0);
      gh0 = fdot2(mk2(wv1[6], wv1[7]), mk2(h01[6], h01[7]), gh0);
      gh1 = fdot2(mk2(wv1[0], wv1[1]), mk2(h11[0], h11[1]), gh1);
      gh1 = fdot2(mk2(wv1[2], wv1[3]), mk2(h11[2], h11[3]), gh1);
      gh1 = fdot2(mk2(wv1[4], wv1[5]), mk2(h11[4], h11[5]), gh1);
      gh1 = fdot2(mk2(wv1[6], wv1[7]), mk2(h11[6], h11[7]), gh1);
      wv0 = n0; wv1 = n1;
    }

    // ---- u quad-reduce + s write ----
    float u0 = u0a + u0b, u1 = u1a + u1b;
    u0 += __shfl_xor(u0, 1, 64); u0 += __shfl_xor(u0, 2, 64);
    u1 += __shfl_xor(u1, 1, 64); u1 += __shfl_xor(u1, 2, 64);
    if (g_u == 0) s_arr[0][k_u >> 6][k_u & 63] = fast_tanh(u0 + b1k);
    else if (g_u == 1) s_arr[1][k_u >> 6][k_u & 63] = fast_tanh(u1 + b1k);
    __syncthreads();

    // ---- Phase B: scores via tanh(u+E) = (s+t)/(1+st) ----
    {
      const int pr = k_u;  // pair 0..255; valid < 254
      if (pr < 254) {
        const int bb = pr & 1;
        const int j = pr >> 1;
        const h4* tp = (const h4*)&tE1[bb][j][g_u * 68];
        const float4* sp = (const float4*)&s_arr[bb][g_u][0];
        const float4* w2p = (const float4*)&w2_lds[g_u * 64];
        float acc0 = 0.f, acc1 = 0.f;
#pragma unroll
        for (int i = 0; i < 16; ++i) {
          h4 tv = tp[i];
          float4 sv = sp[i];
          float4 wv = w2p[i];
          float t0 = (float)tv[0], t1 = (float)tv[1], t2 = (float)tv[2], t3 = (float)tv[3];
          acc0 = fmaf(wv.x * (sv.x + t0), rcp_f(fmaf(sv.x, t0, 1.f)), acc0);
          acc1 = fmaf(wv.y * (sv.y + t1), rcp_f(fmaf(sv.y, t1, 1.f)), acc1);
          acc0 = fmaf(wv.z * (sv.z + t2), rcp_f(fmaf(sv.z, t2, 1.f)), acc0);
          acc1 = fmaf(wv.w * (sv.w + t3), rcp_f(fmaf(sv.w, t3, 1.f)), acc1);
        }
        float acc = acc0 + acc1;
        acc += __shfl_xor(acc, 1, 64);
        acc += __shfl_xor(acc, 2, 64);
        if (g_u == 0) score_s[bb][j] = acc + ba2v;
      }
    }
    __syncthreads();

    // ---- Phase C: softmax, attn write, context dots, y_tilde ----
    {
      const int wv = L >> 6, ln = L & 63;
      if (wv < 2) {
        const int bb = wv;
        const int batch = b0 + bb;
        float x0 = score_s[bb][ln];
        float x1 = (ln < 63) ? score_s[bb][64 + ln] : -3.4e38f;
        float m = fmaxf(x0, x1);
#pragma unroll
        for (int s = 32; s; s >>= 1) m = fmaxf(m, __shfl_xor(m, s, 64));
        float e0 = __expf(x0 - m);
        float e1 = (ln < 63) ? __expf(x1 - m) : 0.f;
        float ssum = e0 + e1;
#pragma unroll
        for (int s = 32; s; s >>= 1) ssum += __shfl_xor(ssum, s, 64);
        float rs = rcp_f(ssum);
        float a0 = e0 * rs, a1 = e1 * rs;
        float* wout = outp + 512 + ((size_t)batch * T127 + t) * T127;
        wout[ln] = a0;
        if (ln < 63) wout[64 + ln] = a1;
        float cw = a0 * p_s[bb][ln] + ((ln < 63) ? a1 * p_s[bb][64 + ln] : 0.f);
#pragma unroll
        for (int s = 32; s; s >>= 1) cw += __shfl_xor(cw, s, 64);
        if (ln == 0) ytil[bb] = cw + wfcy * yh_s[bb][t] + bfc0;
        if (t == T127 - 1) {
          float cq = a0 * q_s[bb][ln] + ((ln < 63) ? a1 * q_s[bb][64 + ln] : 0.f);
#pragma unroll
          for (int s = 32; s; s >>= 1) cq += __shfl_xor(cq, s, 64);
          if (ln == 0) ctxq_s[bb] = cq;
        }
      }
    }
    __syncthreads();

    // ---- Phase D: gates + activations ----
    {
      float g0 = gh0 + wihn * ytil[0] + biasn;
      float g1 = gh1 + wihn * ytil[1] + biasn;
      bool is_g = (L >= 512) && (L < 768);
      float a0 = is_g ? fast_tanh(g0) : fast_sig(g0);
      float a1 = is_g ? fast_tanh(g1) : fast_sig(g1);
      gact[L] = a0;
      gact[1024 + L] = a1;
    }
    __syncthreads();

    // ---- Phase E: LSTM cell update ----
    if (L < 512) {
      const int bb = L >> 8, kk = L & 255;
      float gi = gact[bb * 1024 + kk];
      float gf = gact[bb * 1024 + 256 + kk];
      float gg = gact[bb * 1024 + 512 + kk];
      float go = gact[bb * 1024 + 768 + kk];
      float cn = gf * c_s[bb][kk] + gi * gg;
      float hn = go * fast_tanh(cn);
      c_s[bb][kk] = cn;
      hch[bb][kk >> 7][kk & 127] = (f16)hn;
      hch[bb][2 + (kk >> 7)][kk & 127] = (f16)cn;
      if (t == T127 - 1) {
        float po = Wfcf[kk] * hn;
#pragma unroll
        for (int s = 32; s; s >>= 1) po += __shfl_xor(po, s, 64);
        if ((L & 63) == 0) red[L >> 6] = po;
      }
    }
    __syncthreads();
  }

  // ---------------- final: out = Wfcf[0:256].h + ctx.Wfcf[256:512] + b ----------------
  if (L < 2) {
    float o = red[L * 4] + red[L * 4 + 1] + red[L * 4 + 2] + red[L * 4 + 3] + ctxq_s[L] + bfcf[0];
    outp[b0 + L] = o;
  }
}

extern "C" void kernel_launch(void* const* d_in, const int* in_sizes, int n_in,
                              void* d_out, int out_size, void* d_ws, size_t ws_size,
                              hipStream_t stream) {
  (void)in_sizes; (void)n_in; (void)out_size; (void)ws_size;
  f16* wsW = (f16*)d_ws;  // needs 32*1024*8*2 = 512 KiB
  pack_whh<<<1024, 256, 0, stream>>>((const float*)d_in[7], wsW);
  decoder_kernel<<<256, 1024, 0, stream>>>(
      (const float*)d_in[0], (const float*)d_in[1], (const float*)d_in[2],
      (const float*)d_in[3], (const float*)d_in[4], (const float*)d_in[5],
      (const float*)d_in[6], (const float*)d_in[7], (const float*)d_in[8],
      (const float*)d_in[9], (const float*)d_in[10], (const float*)d_in[11],
      (const float*)d_in[12], (const float*)d_in[13], wsW, (float*)d_out);
}

// Round 5
// 1926.273 us; speedup vs baseline: 2.6924x; 2.6924x over previous
//
#include <hip/hip_runtime.h>

typedef _Float16 f16;
typedef _Float16 h2 __attribute__((ext_vector_type(2)));
typedef _Float16 h4 __attribute__((ext_vector_type(4)));
typedef _Float16 h8 __attribute__((ext_vector_type(8)));

#define T127 127

__device__ __forceinline__ float rcp_f(float x) { return __builtin_amdgcn_rcpf(x); }

__device__ __forceinline__ float fdot2(h2 a, h2 b, float c) {
  return __builtin_amdgcn_fdot2(a, b, c, false);
}
__device__ __forceinline__ h2 mk2(f16 a, f16 b) { h2 v; v[0] = a; v[1] = b; return v; }

__device__ __forceinline__ float fast_tanh(float x) {
  x = fminf(fmaxf(x, -12.f), 12.f);
  float e = __expf(2.f * x);
  return (e - 1.f) * rcp_f(e + 1.f);
}
__device__ __forceinline__ float fast_sig(float x) {
  x = fminf(fmaxf(x, -30.f), 30.f);
  return rcp_f(1.f + __expf(-x));
}

// ---- pack Wa1 c-part fp32 -> fp16, wave-contiguous stream layout ----
// wsA[(it*512 + L)*8 + j] = Wa1[L>>1][256 + (L&1)*128 + it*8 + j], it 0..15
__global__ void pack_wa1c(const float* __restrict__ Wa1, f16* __restrict__ wsA) {
  int tid = blockIdx.x * 256 + threadIdx.x;  // 32 blocks
  int it = tid >> 9, L = tid & 511;
  int k = L >> 1, g2 = L & 1;
  const float* src = Wa1 + (size_t)k * 768 + 256 + g2 * 128 + it * 8;
  f16* dst = wsA + (size_t)tid * 8;
#pragma unroll
  for (int j = 0; j < 8; ++j) dst[j] = (f16)src[j];
}

// ---- pack Whh fp32 -> fp16, wave-contiguous stream layout ----
// wsH[(m*512 + L)*8 + j] = Whh[L + (m&1)*512][(m>>1)*8 + j], m 0..63
__global__ void pack_whh2(const float* __restrict__ Whh, f16* __restrict__ wsH) {
  int tid = blockIdx.x * 256 + threadIdx.x;  // 128 blocks
  int m = tid >> 9, L = tid & 511;
  int row = L + (m & 1) * 512;
  int it = m >> 1;
  const float* src = Whh + (size_t)row * 256 + it * 8;
  f16* dst = wsH + (size_t)tid * 8;
#pragma unroll
  for (int j = 0; j < 8; ++j) dst[j] = (f16)src[j];
}

// 256 blocks x 512 threads, 1 block/CU. WG=512 -> implied min 4 waves/EU ->
// 128-VGPR budget (WG=1024 was hard-clamped to 64 and spilled; rounds 2-4).
// Resident: Wa1-h fp16 (64 VGPRs/lane). Streamed from L2: Wa1-c + Whh
// (packed fp16 in d_ws, wave-contiguous 1-KB reads). tE1 resident in LDS.
__global__ __attribute__((amdgpu_flat_work_group_size(512, 512)))
void decoder_kernel(
    const float* __restrict__ enc,    // [512][127][256]
    const float* __restrict__ yhist,  // [512][127]
    const float* __restrict__ Wa1,    // [256][768]  cols: h|c|e
    const float* __restrict__ ba1,    // [256]
    const float* __restrict__ Wa2,    // [256]
    const float* __restrict__ ba2,    // [1]
    const float* __restrict__ Wih,    // [1024]
    const float* __restrict__ bih,    // [1024]
    const float* __restrict__ bhh,    // [1024]
    const float* __restrict__ Wfc,    // [257]
    const float* __restrict__ bfc,    // [1]
    const float* __restrict__ Wfcf,   // [512]
    const float* __restrict__ bfcf,   // [1]
    const f16* __restrict__ wsA,      // packed Wa1-c [16][512][8]
    const f16* __restrict__ wsH,      // packed Whh   [64][512][8]
    float* __restrict__ outp)         // [512] out ++ [512][127][127] weight
{
  __shared__ __align__(16) f16 tE1[2][T127][272];   // tanh(E1), chunks at g*68
  __shared__ __align__(16) f16 hch[2][4][136];      // h (chunks 0,1) | c (2,3) fp16
  __shared__ __align__(16) float s_arr[2][4][68];   // s = tanh(u+b1)
  __shared__ __align__(16) float score_s[2][128];
  __shared__ __align__(16) float p_s[2][128];       // e . Wfc[0:256]
  __shared__ __align__(16) float q_s[2][128];       // e . Wfcf[256:512]
  __shared__ __align__(16) char ovl[8192];          // est [8][288] f16 UNION gact [2][1024] f32
  __shared__ __align__(16) float w2_lds[256];
  __shared__ __align__(16) float yh_s[2][128];
  __shared__ float ytil[2], ctxq_s[2], red[8];

  float* gact = (float*)ovl;
  f16* est = (f16*)ovl;

  const int L = threadIdx.x;   // 0..511
  const int b0 = blockIdx.x * 2;
  const int kL = L >> 1;       // u-output index 0..255
  const int g2 = L & 1;        // col-half selector (128 cols each)

  // ---------------- init ----------------
  for (int i = L; i < 1088; i += 512) ((f16*)hch)[i] = (f16)0.f;
  if (L < 256) {
    w2_lds[L] = Wa2[L];
    int bb = L >> 7, tt = L & 127;
    if (tt < T127) yh_s[bb][tt] = yhist[(size_t)(b0 + bb) * T127 + tt];
  }
  float c_reg = 0.f;  // fp32 cell state for (bb = L>>8, kk = L&255)

  // ---------------- prologue: tE1 = tanh(e.W1e), p, q ----------------
  {
    h2 we1[64];  // W1e[kL][g2*128 .. +128]
    {
      const float4* wrow = (const float4*)(Wa1 + (size_t)kL * 768 + 512 + g2 * 128);
#pragma unroll
      for (int i = 0; i < 32; ++i) {
        float4 w = wrow[i];
        we1[2 * i]     = mk2((f16)w.x, (f16)w.y);
        we1[2 * i + 1] = mk2((f16)w.z, (f16)w.w);
      }
    }
    const int prow = L >> 6;      // wave id = staged row 0..7
    const int lm = L & 63;
    const int sg = lm >> 4;       // staging chunk 0..3 (72-elem stride)
    const int si = (lm * 4) & 63;

#pragma unroll 1
    for (int tt = 0; tt < 32; ++tt) {
      __syncthreads();
      {  // stage 8 (b,j) rows as fp16: row = bbs*4 + j4, j = tt*4+j4
        int bbs = prow >> 2, j4 = prow & 3, j = tt * 4 + j4;
        float4 v = make_float4(0.f, 0.f, 0.f, 0.f);
        if (j < T127)
          v = *(const float4*)(enc + (((size_t)(b0 + bbs)) * T127 + j) * 256 + lm * 4);
        h4 hv; hv[0] = (f16)v.x; hv[1] = (f16)v.y; hv[2] = (f16)v.z; hv[3] = (f16)v.w;
        *(h4*)(est + prow * 288 + sg * 72 + si) = hv;
      }
      __syncthreads();
      // each lane-pair computes all 8 rows over its 128 cols + pair-reduce
#pragma unroll 1
      for (int P = 0; P < 8; ++P) {
        int bbs = P >> 2, j4 = P & 3, j = tt * 4 + j4;
        const h8* ep = (const h8*)(est + P * 288 + (2 * g2) * 72);
        const h8* ep2 = (const h8*)(est + P * 288 + (2 * g2 + 1) * 72);
        float a0 = 0.f, a1 = 0.f;
#pragma unroll
        for (int r = 0; r < 8; ++r) {
          h8 e8 = ep[r];
          a0 = fdot2(we1[4 * r + 0], mk2(e8[0], e8[1]), a0);
          a1 = fdot2(we1[4 * r + 1], mk2(e8[2], e8[3]), a1);
          a0 = fdot2(we1[4 * r + 2], mk2(e8[4], e8[5]), a0);
          a1 = fdot2(we1[4 * r + 3], mk2(e8[6], e8[7]), a1);
        }
#pragma unroll
        for (int r = 0; r < 8; ++r) {
          h8 e8 = ep2[r];
          a0 = fdot2(we1[32 + 4 * r + 0], mk2(e8[0], e8[1]), a0);
          a1 = fdot2(we1[32 + 4 * r + 1], mk2(e8[2], e8[3]), a1);
          a0 = fdot2(we1[32 + 4 * r + 2], mk2(e8[4], e8[5]), a0);
          a1 = fdot2(we1[32 + 4 * r + 3], mk2(e8[6], e8[7]), a1);
        }
        float acc = a0 + a1;
        acc += __shfl_xor(acc, 1, 64);
        if (g2 == 0 && j < T127)
          tE1[bbs][j][(kL >> 6) * 68 + (kL & 63)] = (f16)fast_tanh(acc);
      }
      {  // p, q for this wave's staged row
        int bbs = prow >> 2, j4 = prow & 3, j = tt * 4 + j4;
        float4 wp4 = *(const float4*)(Wfc + lm * 4);
        float4 wq4 = *(const float4*)(Wfcf + 256 + lm * 4);
        h4 ev = *(const h4*)(est + prow * 288 + sg * 72 + si);
        float pacc = (float)ev[0] * wp4.x + (float)ev[1] * wp4.y + (float)ev[2] * wp4.z + (float)ev[3] * wp4.w;
        float qacc = (float)ev[0] * wq4.x + (float)ev[1] * wq4.y + (float)ev[2] * wq4.z + (float)ev[3] * wq4.w;
#pragma unroll
        for (int s = 32; s; s >>= 1) {
          pacc += __shfl_xor(pacc, s, 64);
          qacc += __shfl_xor(qacc, s, 64);
        }
        if (lm == 0 && j < T127) { p_s[bbs][j] = pacc; q_s[bbs][j] = qacc; }
      }
    }
  }
  __syncthreads();

  // ---------------- persistent registers ----------------
  h2 w1h[64];  // Wa1-h[kL][g2*128 .. +128] fp16 (64 VGPRs)
  {
    const float4* wrow = (const float4*)(Wa1 + (size_t)kL * 768 + g2 * 128);
#pragma unroll
    for (int i = 0; i < 32; ++i) {
      float4 w = wrow[i];
      w1h[2 * i]     = mk2((f16)w.x, (f16)w.y);
      w1h[2 * i + 1] = mk2((f16)w.z, (f16)w.w);
    }
  }
  const float b1k = ba1[kL];
  const float wihA = Wih[L];
  const float wihB = Wih[512 + L];
  const float biasA = bih[L] + bhh[L];
  const float biasB = bih[512 + L] + bhh[512 + L];
  const float ba2v = ba2[0];
  const float wfcy = Wfc[256];
  const float bfc0 = bfc[0];
  const int g_u = L & 3;
  __syncthreads();

  // ---------------- 127 sequential steps ----------------
#pragma unroll 1
  for (int t = 0; t < T127; ++t) {
    const h8* wA = (const h8*)wsA + L;  // Wa1-c chunk it at wA[it*512]
    const h8* wH = (const h8*)wsH + L;  // Whh chunk m at wH[m*512]
    h8 a0 = wA[0], a1 = wA[512];
    h8 p0 = wH[0], p1 = wH[512], p2 = wH[1024], p3 = wH[1536];

    // ---- Phase A1: u = Wa1h.h (resident) + Wa1c.c (streamed) ----
    float u0a = 0.f, u0b = 0.f, u1a = 0.f, u1b = 0.f;
    {
      const h8* hp0 = (const h8*)&hch[0][g2][0];
      const h8* hp1 = (const h8*)&hch[1][g2][0];
#pragma unroll
      for (int r = 0; r < 16; ++r) {
        h8 x = hp0[r];
        u0a = fdot2(w1h[4 * r + 0], mk2(x[0], x[1]), u0a);
        u0b = fdot2(w1h[4 * r + 1], mk2(x[2], x[3]), u0b);
        u0a = fdot2(w1h[4 * r + 2], mk2(x[4], x[5]), u0a);
        u0b = fdot2(w1h[4 * r + 3], mk2(x[6], x[7]), u0b);
        h8 y = hp1[r];
        u1a = fdot2(w1h[4 * r + 0], mk2(y[0], y[1]), u1a);
        u1b = fdot2(w1h[4 * r + 1], mk2(y[2], y[3]), u1b);
        u1a = fdot2(w1h[4 * r + 2], mk2(y[4], y[5]), u1a);
        u1b = fdot2(w1h[4 * r + 3], mk2(y[6], y[7]), u1b);
      }
    }
    {
      const h8* cp0 = (const h8*)&hch[0][2 + g2][0];
      const h8* cp1 = (const h8*)&hch[1][2 + g2][0];
#pragma unroll 1
      for (int it = 0; it < 16; ++it) {
        h8 nxt = wA[((it + 2) & 15) * 512];
        h8 c0 = cp0[it], c1 = cp1[it];
        u0a = fdot2(mk2(a0[0], a0[1]), mk2(c0[0], c0[1]), u0a);
        u0b = fdot2(mk2(a0[2], a0[3]), mk2(c0[2], c0[3]), u0b);
        u0a = fdot2(mk2(a0[4], a0[5]), mk2(c0[4], c0[5]), u0a);
        u0b = fdot2(mk2(a0[6], a0[7]), mk2(c0[6], c0[7]), u0b);
        u1a = fdot2(mk2(a0[0], a0[1]), mk2(c1[0], c1[1]), u1a);
        u1b = fdot2(mk2(a0[2], a0[3]), mk2(c1[2], c1[3]), u1b);
        u1a = fdot2(mk2(a0[4], a0[5]), mk2(c1[4], c1[5]), u1a);
        u1b = fdot2(mk2(a0[6], a0[7]), mk2(c1[6], c1[7]), u1b);
        a0 = a1; a1 = nxt;
      }
    }

    // ---- Phase A2: gh = Whh.h for rows L and L+512, both batches ----
    float ghA0 = 0.f, ghA1 = 0.f, ghB0 = 0.f, ghB1 = 0.f;
#pragma unroll 1
    for (int m = 0; m < 64; m += 2) {
      h8 n0 = wH[((m + 4) & 63) * 512];
      h8 n1 = wH[((m + 5) & 63) * 512];
      int it = m >> 1;  // col chunk 0..31
      int ch = it >> 4, off = (it & 15) * 8;
      h8 x = *(const h8*)&hch[0][ch][off];
      h8 y = *(const h8*)&hch[1][ch][off];
      ghA0 = fdot2(mk2(p0[0], p0[1]), mk2(x[0], x[1]), ghA0);
      ghA0 = fdot2(mk2(p0[2], p0[3]), mk2(x[2], x[3]), ghA0);
      ghA0 = fdot2(mk2(p0[4], p0[5]), mk2(x[4], x[5]), ghA0);
      ghA0 = fdot2(mk2(p0[6], p0[7]), mk2(x[6], x[7]), ghA0);
      ghA1 = fdot2(mk2(p0[0], p0[1]), mk2(y[0], y[1]), ghA1);
      ghA1 = fdot2(mk2(p0[2], p0[3]), mk2(y[2], y[3]), ghA1);
      ghA1 = fdot2(mk2(p0[4], p0[5]), mk2(y[4], y[5]), ghA1);
      ghA1 = fdot2(mk2(p0[6], p0[7]), mk2(y[6], y[7]), ghA1);
      ghB0 = fdot2(mk2(p1[0], p1[1]), mk2(x[0], x[1]), ghB0);
      ghB0 = fdot2(mk2(p1[2], p1[3]), mk2(x[2], x[3]), ghB0);
      ghB0 = fdot2(mk2(p1[4], p1[5]), mk2(x[4], x[5]), ghB0);
      ghB0 = fdot2(mk2(p1[6], p1[7]), mk2(x[6], x[7]), ghB0);
      ghB1 = fdot2(mk2(p1[0], p1[1]), mk2(y[0], y[1]), ghB1);
      ghB1 = fdot2(mk2(p1[2], p1[3]), mk2(y[2], y[3]), ghB1);
      ghB1 = fdot2(mk2(p1[4], p1[5]), mk2(y[4], y[5]), ghB1);
      ghB1 = fdot2(mk2(p1[6], p1[7]), mk2(y[6], y[7]), ghB1);
      p0 = p2; p1 = p3; p2 = n0; p3 = n1;
    }

    // ---- u pair-reduce + s write ----
    {
      float u0 = u0a + u0b, u1 = u1a + u1b;
      u0 += __shfl_xor(u0, 1, 64);
      u1 += __shfl_xor(u1, 1, 64);
      if (g2 == 0) s_arr[0][kL >> 6][kL & 63] = fast_tanh(u0 + b1k);
      else         s_arr[1][kL >> 6][kL & 63] = fast_tanh(u1 + b1k);
    }
    __syncthreads();

    // ---- Phase B: scores via tanh(u+E) = (s+t)/(1+st), 2 passes ----
#pragma unroll
    for (int half = 0; half < 2; ++half) {
      const int pr = (L >> 2) + half * 128;  // pair 0..255; valid < 254
      if (pr < 254) {
        const int bb = pr & 1;
        const int j = pr >> 1;
        const h4* tp = (const h4*)&tE1[bb][j][g_u * 68];
        const float4* sp = (const float4*)&s_arr[bb][g_u][0];
        const float4* w2p = (const float4*)&w2_lds[g_u * 64];
        float acc0 = 0.f, acc1 = 0.f;
#pragma unroll
        for (int i = 0; i < 16; ++i) {
          h4 tv = tp[i];
          float4 sv = sp[i];
          float4 wv = w2p[i];
          float t0 = (float)tv[0], t1 = (float)tv[1], t2 = (float)tv[2], t3 = (float)tv[3];
          acc0 = fmaf(wv.x * (sv.x + t0), rcp_f(fmaf(sv.x, t0, 1.f)), acc0);
          acc1 = fmaf(wv.y * (sv.y + t1), rcp_f(fmaf(sv.y, t1, 1.f)), acc1);
          acc0 = fmaf(wv.z * (sv.z + t2), rcp_f(fmaf(sv.z, t2, 1.f)), acc0);
          acc1 = fmaf(wv.w * (sv.w + t3), rcp_f(fmaf(sv.w, t3, 1.f)), acc1);
        }
        float acc = acc0 + acc1;
        acc += __shfl_xor(acc, 1, 64);
        acc += __shfl_xor(acc, 2, 64);
        if (g_u == 0) score_s[bb][j] = acc + ba2v;
      }
    }
    __syncthreads();

    // ---- Phase C: softmax, attn write, context dots, y_tilde ----
    {
      const int wv = L >> 6, ln = L & 63;
      if (wv < 2) {
        const int bb = wv;
        const int batch = b0 + bb;
        float x0 = score_s[bb][ln];
        float x1 = (ln < 63) ? score_s[bb][64 + ln] : -3.4e38f;
        float m = fmaxf(x0, x1);
#pragma unroll
        for (int s = 32; s; s >>= 1) m = fmaxf(m, __shfl_xor(m, s, 64));
        float e0 = __expf(x0 - m);
        float e1 = (ln < 63) ? __expf(x1 - m) : 0.f;
        float ssum = e0 + e1;
#pragma unroll
        for (int s = 32; s; s >>= 1) ssum += __shfl_xor(ssum, s, 64);
        float rs = rcp_f(ssum);
        float aa0 = e0 * rs, aa1 = e1 * rs;
        float* wout = outp + 512 + ((size_t)batch * T127 + t) * T127;
        wout[ln] = aa0;
        if (ln < 63) wout[64 + ln] = aa1;
        float cw = aa0 * p_s[bb][ln] + ((ln < 63) ? aa1 * p_s[bb][64 + ln] : 0.f);
#pragma unroll
        for (int s = 32; s; s >>= 1) cw += __shfl_xor(cw, s, 64);
        if (ln == 0) ytil[bb] = cw + wfcy * yh_s[bb][t] + bfc0;
        if (t == T127 - 1) {
          float cq = aa0 * q_s[bb][ln] + ((ln < 63) ? aa1 * q_s[bb][64 + ln] : 0.f);
#pragma unroll
          for (int s = 32; s; s >>= 1) cq += __shfl_xor(cq, s, 64);
          if (ln == 0) ctxq_s[bb] = cq;
        }
      }
    }
    __syncthreads();

    // ---- Phase D: gates for rows L, L+512 both batches ----
    {
      float yt0 = ytil[0], yt1 = ytil[1];
      float gA0 = ghA0 + wihA * yt0 + biasA;  // rows 0..511: i|f -> sigmoid
      float gA1 = ghA1 + wihA * yt1 + biasA;
      float gB0 = ghB0 + wihB * yt0 + biasB;  // rows 512..1023: g|o
      float gB1 = ghB1 + wihB * yt1 + biasB;
      float aA0 = fast_sig(gA0), aA1 = fast_sig(gA1);
      bool isg = (L < 256);  // rows 512..767 = g-gate -> tanh
      float aB0 = isg ? fast_tanh(gB0) : fast_sig(gB0);
      float aB1 = isg ? fast_tanh(gB1) : fast_sig(gB1);
      gact[0 * 1024 + L] = aA0;
      gact[1 * 1024 + L] = aA1;
      gact[0 * 1024 + 512 + L] = aB0;
      gact[1 * 1024 + 512 + L] = aB1;
    }
    __syncthreads();

    // ---- Phase E: LSTM cell update (lane owns (bb, kk), c in register) ----
    {
      const int bb = L >> 8, kk = L & 255;
      float gi = gact[bb * 1024 + kk];
      float gf = gact[bb * 1024 + 256 + kk];
      float gg = gact[bb * 1024 + 512 + kk];
      float go = gact[bb * 1024 + 768 + kk];
      float cn = gf * c_reg + gi * gg;
      float hn = go * fast_tanh(cn);
      c_reg = cn;
      hch[bb][kk >> 7][kk & 127] = (f16)hn;
      hch[bb][2 + (kk >> 7)][kk & 127] = (f16)cn;
      if (t == T127 - 1) {
        float po = Wfcf[kk] * hn;
#pragma unroll
        for (int s = 32; s; s >>= 1) po += __shfl_xor(po, s, 64);
        if ((L & 63) == 0) red[L >> 6] = po;
      }
    }
    __syncthreads();
  }

  // ---------------- final: out = Wfcf[0:256].h + ctx.Wfcf[256:512] + b ----------------
  if (L < 2) {
    float o = red[L * 4] + red[L * 4 + 1] + red[L * 4 + 2] + red[L * 4 + 3] + ctxq_s[L] + bfcf[0];
    outp[b0 + L] = o;
  }
}

extern "C" void kernel_launch(void* const* d_in, const int* in_sizes, int n_in,
                              void* d_out, int out_size, void* d_ws, size_t ws_size,
                              hipStream_t stream) {
  (void)in_sizes; (void)n_in; (void)out_size; (void)ws_size;
  f16* wsA = (f16*)d_ws;            // 16*512*8 = 65536 halves (128 KiB)
  f16* wsH = wsA + 65536;           // 64*512*8 = 262144 halves (512 KiB)
  pack_wa1c<<<32, 256, 0, stream>>>((const float*)d_in[2], wsA);
  pack_whh2<<<128, 256, 0, stream>>>((const float*)d_in[7], wsH);
  decoder_kernel<<<256, 512, 0, stream>>>(
      (const float*)d_in[0], (const float*)d_in[1], (const float*)d_in[2],
      (const float*)d_in[3], (const float*)d_in[4], (const float*)d_in[5],
      (const float*)d_in[6], (const float*)d_in[8], (const float*)d_in[9],
      (const float*)d_in[10], (const float*)d_in[11], (const float*)d_in[12],
      (const float*)d_in[13], wsA, wsH, (float*)d_out);
}

// Round 6
// 1825.248 us; speedup vs baseline: 2.8414x; 1.0553x over previous
//
#include <hip/hip_runtime.h>

typedef _Float16 f16;
typedef _Float16 h2 __attribute__((ext_vector_type(2)));
typedef _Float16 h4 __attribute__((ext_vector_type(4)));
typedef _Float16 h8 __attribute__((ext_vector_type(8)));

#define T127 127

__device__ __forceinline__ float rcp_f(float x) { return __builtin_amdgcn_rcpf(x); }

__device__ __forceinline__ float fdot2(h2 a, h2 b, float c) {
  return __builtin_amdgcn_fdot2(a, b, c, false);
}
__device__ __forceinline__ h2 mk2(f16 a, f16 b) { h2 v; v[0] = a; v[1] = b; return v; }

__device__ __forceinline__ float fast_tanh(float x) {
  x = fminf(fmaxf(x, -12.f), 12.f);
  float e = __expf(2.f * x);
  return (e - 1.f) * rcp_f(e + 1.f);
}
__device__ __forceinline__ float fast_sig(float x) {
  x = fminf(fmaxf(x, -30.f), 30.f);
  return rcp_f(1.f + __expf(-x));
}

// ---- pack Wa1 c-part fp32 -> fp16, wave-contiguous stream layout ----
// wsA[(it*512 + L)*8 + j] = Wa1[L>>1][256 + (L&1)*128 + it*8 + j], it 0..15
__global__ void pack_wa1c(const float* __restrict__ Wa1, f16* __restrict__ wsA) {
  int tid = blockIdx.x * 256 + threadIdx.x;  // 32 blocks
  int it = tid >> 9, L = tid & 511;
  int k = L >> 1, g2 = L & 1;
  const float* src = Wa1 + (size_t)k * 768 + 256 + g2 * 128 + it * 8;
  f16* dst = wsA + (size_t)tid * 8;
#pragma unroll
  for (int j = 0; j < 8; ++j) dst[j] = (f16)src[j];
}

// ---- pack Whh fp32 -> fp16, wave-contiguous stream layout ----
// wsH[(m*512 + L)*8 + j] = Whh[L + (m&1)*512][(m>>1)*8 + j], m 0..63
__global__ void pack_whh2(const float* __restrict__ Whh, f16* __restrict__ wsH) {
  int tid = blockIdx.x * 256 + threadIdx.x;  // 128 blocks
  int m = tid >> 9, L = tid & 511;
  int row = L + (m & 1) * 512;
  int it = m >> 1;
  const float* src = Whh + (size_t)row * 256 + it * 8;
  f16* dst = wsH + (size_t)tid * 8;
#pragma unroll
  for (int j = 0; j < 8; ++j) dst[j] = (f16)src[j];
}

// 256 blocks x 512 threads, 1 block/CU. WG=512 -> 128-VGPR budget (WG=1024
// was clamped to 64 VGPRs and spilled; rounds 2-4. Keep WG=512.)
// Round-6: Whh L2 stream + gh dots fused INTO the attention-score loop so the
// ~4 us/step per-CU L2-port floor shadows all attention VALU/LDS work;
// redundant per-wave softmax (ytil in registers) removes a barrier;
// tE1 row stride 280 halves (140 dw == 12 banks) -> ~2-way (free) conflicts.
__global__ __attribute__((amdgpu_flat_work_group_size(512, 512)))
void decoder_kernel(
    const float* __restrict__ enc,    // [512][127][256]
    const float* __restrict__ yhist,  // [512][127]
    const float* __restrict__ Wa1,    // [256][768]  cols: h|c|e
    const float* __restrict__ ba1,    // [256]
    const float* __restrict__ Wa2,    // [256]
    const float* __restrict__ ba2,    // [1]
    const float* __restrict__ Wih,    // [1024]
    const float* __restrict__ bih,    // [1024]
    const float* __restrict__ bhh,    // [1024]
    const float* __restrict__ Wfc,    // [257]
    const float* __restrict__ bfc,    // [1]
    const float* __restrict__ Wfcf,   // [512]
    const float* __restrict__ bfcf,   // [1]
    const f16* __restrict__ wsA,      // packed Wa1-c [16][512][8]
    const f16* __restrict__ wsH,      // packed Whh   [64][512][8]
    float* __restrict__ outp)         // [512] out ++ [512][127][127] weight
{
  __shared__ __align__(16) f16 tE1[2][T127][280];   // tanh(E1), chunks at g*68
  __shared__ __align__(16) f16 hch[2][4][136];      // h (chunks 0,1) | c (2,3) fp16
  __shared__ __align__(16) float s_arr[2][4][68];   // s = tanh(u+b1)
  __shared__ __align__(16) float score_s[2][128];
  __shared__ __align__(16) float p_s[2][128];       // e . Wfc[0:256]
  __shared__ __align__(16) float q_s[2][128];       // e . Wfcf[256:512]
  __shared__ __align__(16) char ovl[8192];          // est [8][288] f16 UNION gact [2][1024] f32
  __shared__ __align__(16) float w2_lds[256];
  __shared__ __align__(16) float yh_s[2][128];
  __shared__ float ctxq_s[2], red[8];

  float* gact = (float*)ovl;
  f16* est = (f16*)ovl;

  const int L = threadIdx.x;   // 0..511
  const int b0 = blockIdx.x * 2;
  const int kL = L >> 1;       // u-output index 0..255
  const int g2 = L & 1;        // col-half selector (128 cols each)

  // ---------------- init ----------------
  for (int i = L; i < 1088; i += 512) ((f16*)hch)[i] = (f16)0.f;
  if (L < 256) {
    w2_lds[L] = Wa2[L];
    int bb = L >> 7, tt = L & 127;
    if (tt < T127) yh_s[bb][tt] = yhist[(size_t)(b0 + bb) * T127 + tt];
  }
  float c_reg = 0.f;  // fp32 cell state for (bb = L>>8, kk = L&255)

  // ---------------- prologue: tE1 = tanh(e.W1e), p, q ----------------
  {
    h2 we1[64];  // W1e[kL][g2*128 .. +128]
    {
      const float4* wrow = (const float4*)(Wa1 + (size_t)kL * 768 + 512 + g2 * 128);
#pragma unroll
      for (int i = 0; i < 32; ++i) {
        float4 w = wrow[i];
        we1[2 * i]     = mk2((f16)w.x, (f16)w.y);
        we1[2 * i + 1] = mk2((f16)w.z, (f16)w.w);
      }
    }
    const int prow = L >> 6;      // wave id = staged row 0..7
    const int lm = L & 63;
    const int sg = lm >> 4;       // staging chunk 0..3 (72-elem stride)
    const int si = (lm * 4) & 63;

#pragma unroll 1
    for (int tt = 0; tt < 32; ++tt) {
      __syncthreads();
      {  // stage 8 (b,j) rows as fp16: row = bbs*4 + j4, j = tt*4+j4
        int bbs = prow >> 2, j4 = prow & 3, j = tt * 4 + j4;
        float4 v = make_float4(0.f, 0.f, 0.f, 0.f);
        if (j < T127)
          v = *(const float4*)(enc + (((size_t)(b0 + bbs)) * T127 + j) * 256 + lm * 4);
        h4 hv; hv[0] = (f16)v.x; hv[1] = (f16)v.y; hv[2] = (f16)v.z; hv[3] = (f16)v.w;
        *(h4*)(est + prow * 288 + sg * 72 + si) = hv;
      }
      __syncthreads();
#pragma unroll 1
      for (int P = 0; P < 8; ++P) {
        int bbs = P >> 2, j4 = P & 3, j = tt * 4 + j4;
        const h8* ep = (const h8*)(est + P * 288 + (2 * g2) * 72);
        const h8* ep2 = (const h8*)(est + P * 288 + (2 * g2 + 1) * 72);
        float a0 = 0.f, a1 = 0.f;
#pragma unroll
        for (int r = 0; r < 8; ++r) {
          h8 e8 = ep[r];
          a0 = fdot2(we1[4 * r + 0], mk2(e8[0], e8[1]), a0);
          a1 = fdot2(we1[4 * r + 1], mk2(e8[2], e8[3]), a1);
          a0 = fdot2(we1[4 * r + 2], mk2(e8[4], e8[5]), a0);
          a1 = fdot2(we1[4 * r + 3], mk2(e8[6], e8[7]), a1);
        }
#pragma unroll
        for (int r = 0; r < 8; ++r) {
          h8 e8 = ep2[r];
          a0 = fdot2(we1[32 + 4 * r + 0], mk2(e8[0], e8[1]), a0);
          a1 = fdot2(we1[32 + 4 * r + 1], mk2(e8[2], e8[3]), a1);
          a0 = fdot2(we1[32 + 4 * r + 2], mk2(e8[4], e8[5]), a0);
          a1 = fdot2(we1[32 + 4 * r + 3], mk2(e8[6], e8[7]), a1);
        }
        float acc = a0 + a1;
        acc += __shfl_xor(acc, 1, 64);
        if (g2 == 0 && j < T127)
          tE1[bbs][j][(kL >> 6) * 68 + (kL & 63)] = (f16)fast_tanh(acc);
      }
      {  // p, q for this wave's staged row
        int bbs = prow >> 2, j4 = prow & 3, j = tt * 4 + j4;
        float4 wp4 = *(const float4*)(Wfc + lm * 4);
        float4 wq4 = *(const float4*)(Wfcf + 256 + lm * 4);
        h4 ev = *(const h4*)(est + prow * 288 + sg * 72 + si);
        float pacc = (float)ev[0] * wp4.x + (float)ev[1] * wp4.y + (float)ev[2] * wp4.z + (float)ev[3] * wp4.w;
        float qacc = (float)ev[0] * wq4.x + (float)ev[1] * wq4.y + (float)ev[2] * wq4.z + (float)ev[3] * wq4.w;
#pragma unroll
        for (int s = 32; s; s >>= 1) {
          pacc += __shfl_xor(pacc, s, 64);
          qacc += __shfl_xor(qacc, s, 64);
        }
        if (lm == 0 && j < T127) { p_s[bbs][j] = pacc; q_s[bbs][j] = qacc; }
      }
    }
  }
  __syncthreads();

  // ---------------- persistent registers ----------------
  h2 w1h[64];  // Wa1-h[kL][g2*128 .. +128] fp16 (64 VGPRs)
  {
    const float4* wrow = (const float4*)(Wa1 + (size_t)kL * 768 + g2 * 128);
#pragma unroll
    for (int i = 0; i < 32; ++i) {
      float4 w = wrow[i];
      w1h[2 * i]     = mk2((f16)w.x, (f16)w.y);
      w1h[2 * i + 1] = mk2((f16)w.z, (f16)w.w);
    }
  }
  const float b1k = ba1[kL];
  const float wihA = Wih[L];
  const float wihB = Wih[512 + L];
  const float biasA = bih[L] + bhh[L];
  const float biasB = bih[512 + L] + bhh[512 + L];
  const float ba2v = ba2[0];
  const float wfcy = Wfc[256];
  const float bfc0 = bfc[0];
  const int g_u = L & 3;
  __syncthreads();

  // ---------------- 127 sequential steps ----------------
#pragma unroll 1
  for (int t = 0; t < T127; ++t) {
    const h8* wA = (const h8*)wsA + L;  // Wa1-c chunk it at wA[it*512]
    const h8* wH = (const h8*)wsH + L;  // Whh chunk m at wH[m*512]
    h8 a0 = wA[0], a1 = wA[512];
    h8 p0 = wH[0], p1 = wH[512];        // fused-loop prefetch, in flight thru A1

    // ---- Phase A1: u = Wa1h.h (resident) + Wa1c.c (streamed) ----
    float u0a = 0.f, u0b = 0.f, u1a = 0.f, u1b = 0.f;
    {
      const h8* hp0 = (const h8*)&hch[0][g2][0];
      const h8* hp1 = (const h8*)&hch[1][g2][0];
#pragma unroll
      for (int r = 0; r < 16; ++r) {
        h8 x = hp0[r];
        u0a = fdot2(w1h[4 * r + 0], mk2(x[0], x[1]), u0a);
        u0b = fdot2(w1h[4 * r + 1], mk2(x[2], x[3]), u0b);
        u0a = fdot2(w1h[4 * r + 2], mk2(x[4], x[5]), u0a);
        u0b = fdot2(w1h[4 * r + 3], mk2(x[6], x[7]), u0b);
        h8 y = hp1[r];
        u1a = fdot2(w1h[4 * r + 0], mk2(y[0], y[1]), u1a);
        u1b = fdot2(w1h[4 * r + 1], mk2(y[2], y[3]), u1b);
        u1a = fdot2(w1h[4 * r + 2], mk2(y[4], y[5]), u1a);
        u1b = fdot2(w1h[4 * r + 3], mk2(y[6], y[7]), u1b);
      }
    }
    {
      const h8* cp0 = (const h8*)&hch[0][2 + g2][0];
      const h8* cp1 = (const h8*)&hch[1][2 + g2][0];
#pragma unroll 1
      for (int it = 0; it < 16; ++it) {
        h8 nxt = wA[((it + 2) & 15) * 512];
        h8 c0 = cp0[it], c1 = cp1[it];
        u0a = fdot2(mk2(a0[0], a0[1]), mk2(c0[0], c0[1]), u0a);
        u0b = fdot2(mk2(a0[2], a0[3]), mk2(c0[2], c0[3]), u0b);
        u0a = fdot2(mk2(a0[4], a0[5]), mk2(c0[4], c0[5]), u0a);
        u0b = fdot2(mk2(a0[6], a0[7]), mk2(c0[6], c0[7]), u0b);
        u1a = fdot2(mk2(a0[0], a0[1]), mk2(c1[0], c1[1]), u1a);
        u1b = fdot2(mk2(a0[2], a0[3]), mk2(c1[2], c1[3]), u1b);
        u1a = fdot2(mk2(a0[4], a0[5]), mk2(c1[4], c1[5]), u1a);
        u1b = fdot2(mk2(a0[6], a0[7]), mk2(c1[6], c1[7]), u1b);
        a0 = a1; a1 = nxt;
      }
    }
    {
      float u0 = u0a + u0b, u1 = u1a + u1b;
      u0 += __shfl_xor(u0, 1, 64);
      u1 += __shfl_xor(u1, 1, 64);
      if (g2 == 0) s_arr[0][kL >> 6][kL & 63] = fast_tanh(u0 + b1k);
      else         s_arr[1][kL >> 6][kL & 63] = fast_tanh(u1 + b1k);
    }
    __syncthreads();  // #1: s_arr visible

    // ---- Fused: attention scores + Whh L2 stream + gh dots ----
    float ghA0 = 0.f, ghA1 = 0.f, ghB0 = 0.f, ghB1 = 0.f;
    float acc0 = 0.f, acc1 = 0.f;
    int pr = L >> 2;
    int bbB = pr & 1, jB = pr >> 1;
    const h4* tp = (const h4*)&tE1[bbB][jB][g_u * 68];
    const float4* sp = (const float4*)&s_arr[bbB][g_u][0];
    const float4* w2p = (const float4*)&w2_lds[g_u * 64];
#pragma unroll 1
    for (int i = 0; i < 32; ++i) {
      int m = 2 * i;
      h8 n0 = wH[((m + 2) & 63) * 512];
      h8 n1 = wH[((m + 3) & 63) * 512];
      int ch = i >> 4, off = (i & 15) * 8;
      h8 x = *(const h8*)&hch[0][ch][off];
      h8 y = *(const h8*)&hch[1][ch][off];
      // gh: rows L (p0) and L+512 (p1), col chunk i, both batches
      ghA0 = fdot2(mk2(p0[0], p0[1]), mk2(x[0], x[1]), ghA0);
      ghA0 = fdot2(mk2(p0[2], p0[3]), mk2(x[2], x[3]), ghA0);
      ghA0 = fdot2(mk2(p0[4], p0[5]), mk2(x[4], x[5]), ghA0);
      ghA0 = fdot2(mk2(p0[6], p0[7]), mk2(x[6], x[7]), ghA0);
      ghA1 = fdot2(mk2(p0[0], p0[1]), mk2(y[0], y[1]), ghA1);
      ghA1 = fdot2(mk2(p0[2], p0[3]), mk2(y[2], y[3]), ghA1);
      ghA1 = fdot2(mk2(p0[4], p0[5]), mk2(y[4], y[5]), ghA1);
      ghA1 = fdot2(mk2(p0[6], p0[7]), mk2(y[6], y[7]), ghA1);
      ghB0 = fdot2(mk2(p1[0], p1[1]), mk2(x[0], x[1]), ghB0);
      ghB0 = fdot2(mk2(p1[2], p1[3]), mk2(x[2], x[3]), ghB0);
      ghB0 = fdot2(mk2(p1[4], p1[5]), mk2(x[4], x[5]), ghB0);
      ghB0 = fdot2(mk2(p1[6], p1[7]), mk2(x[6], x[7]), ghB0);
      ghB1 = fdot2(mk2(p1[0], p1[1]), mk2(y[0], y[1]), ghB1);
      ghB1 = fdot2(mk2(p1[2], p1[3]), mk2(y[2], y[3]), ghB1);
      ghB1 = fdot2(mk2(p1[4], p1[5]), mk2(y[4], y[5]), ghB1);
      ghB1 = fdot2(mk2(p1[6], p1[7]), mk2(y[6], y[7]), ghB1);
      // B slice: one h4 column-group of tanh(u+E) = (s+t)/(1+st)
      {
        int ii = i & 15;
        h4 tv = tp[ii];
        float4 sv = sp[ii];
        float4 wv = w2p[ii];
        float t0 = (float)tv[0], t1 = (float)tv[1], t2 = (float)tv[2], t3 = (float)tv[3];
        acc0 = fmaf(wv.x * (sv.x + t0), rcp_f(fmaf(sv.x, t0, 1.f)), acc0);
        acc1 = fmaf(wv.y * (sv.y + t1), rcp_f(fmaf(sv.y, t1, 1.f)), acc1);
        acc0 = fmaf(wv.z * (sv.z + t2), rcp_f(fmaf(sv.z, t2, 1.f)), acc0);
        acc1 = fmaf(wv.w * (sv.w + t3), rcp_f(fmaf(sv.w, t3, 1.f)), acc1);
        if (ii == 15) {
          float acc = acc0 + acc1;
          acc += __shfl_xor(acc, 1, 64);
          acc += __shfl_xor(acc, 2, 64);
          if (g_u == 0 && pr < 254) score_s[bbB][jB] = acc + ba2v;
          acc0 = 0.f; acc1 = 0.f;
          pr = (L >> 2) + 128;
          int prc = (pr < 254) ? pr : 253;
          bbB = prc & 1; jB = prc >> 1;
          tp = (const h4*)&tE1[bbB][jB][g_u * 68];
          sp = (const float4*)&s_arr[bbB][g_u][0];
        }
      }
      p0 = n0; p1 = n1;
    }
    __syncthreads();  // #2: score_s visible

    // ---- Phase C (redundant per wave): softmax -> attn, ytil in regs ----
    float ytil0, ytil1;
    {
      const int ln = L & 63;
      const int wv = L >> 6;
#pragma unroll
      for (int bb = 0; bb < 2; ++bb) {
        float x0 = score_s[bb][ln];
        float e0 = __expf(x0);
        float e1 = (ln < 63) ? __expf(score_s[bb][64 + ln]) : 0.f;
        float ssum = e0 + e1;
#pragma unroll
        for (int s = 32; s; s >>= 1) ssum += __shfl_xor(ssum, s, 64);
        float rs = rcp_f(ssum);
        float aa0 = e0 * rs, aa1 = e1 * rs;
        if (wv == bb) {
          float* wout = outp + 512 + ((size_t)(b0 + bb) * T127 + t) * T127;
          wout[ln] = aa0;
          if (ln < 63) wout[64 + ln] = aa1;
        }
        float cw = aa0 * p_s[bb][ln] + ((ln < 63) ? aa1 * p_s[bb][64 + ln] : 0.f);
#pragma unroll
        for (int s = 32; s; s >>= 1) cw += __shfl_xor(cw, s, 64);
        float yt = cw + wfcy * yh_s[bb][t] + bfc0;
        if (bb == 0) ytil0 = yt; else ytil1 = yt;
        if (t == T127 - 1) {
          float cq = aa0 * q_s[bb][ln] + ((ln < 63) ? aa1 * q_s[bb][64 + ln] : 0.f);
#pragma unroll
          for (int s = 32; s; s >>= 1) cq += __shfl_xor(cq, s, 64);
          if (L == 0) ctxq_s[bb] = cq;
        }
      }
    }

    // ---- Phase D: gates for rows L, L+512 both batches ----
    {
      float gA0 = ghA0 + wihA * ytil0 + biasA;  // rows 0..511: i|f -> sigmoid
      float gA1 = ghA1 + wihA * ytil1 + biasA;
      float gB0 = ghB0 + wihB * ytil0 + biasB;  // rows 512..1023: g|o
      float gB1 = ghB1 + wihB * ytil1 + biasB;
      float aA0 = fast_sig(gA0), aA1 = fast_sig(gA1);
      bool isg = (L < 256);  // rows 512..767 = g-gate -> tanh
      float aB0 = isg ? fast_tanh(gB0) : fast_sig(gB0);
      float aB1 = isg ? fast_tanh(gB1) : fast_sig(gB1);
      gact[0 * 1024 + L] = aA0;
      gact[1 * 1024 + L] = aA1;
      gact[0 * 1024 + 512 + L] = aB0;
      gact[1 * 1024 + 512 + L] = aB1;
    }
    __syncthreads();  // #3: gact visible

    // ---- Phase E: LSTM cell update (lane owns (bb, kk), c in register) ----
    {
      const int bb = L >> 8, kk = L & 255;
      float gi = gact[bb * 1024 + kk];
      float gf = gact[bb * 1024 + 256 + kk];
      float gg = gact[bb * 1024 + 512 + kk];
      float go = gact[bb * 1024 + 768 + kk];
      float cn = gf * c_reg + gi * gg;
      float hn = go * fast_tanh(cn);
      c_reg = cn;
      hch[bb][kk >> 7][kk & 127] = (f16)hn;
      hch[bb][2 + (kk >> 7)][kk & 127] = (f16)cn;
      if (t == T127 - 1) {
        float po = Wfcf[kk] * hn;
#pragma unroll
        for (int s = 32; s; s >>= 1) po += __shfl_xor(po, s, 64);
        if ((L & 63) == 0) red[L >> 6] = po;
      }
    }
    __syncthreads();  // #4: hch visible for next step
  }

  // ---------------- final: out = Wfcf[0:256].h + ctx.Wfcf[256:512] + b ----------------
  if (L < 2) {
    float o = red[L * 4] + red[L * 4 + 1] + red[L * 4 + 2] + red[L * 4 + 3] + ctxq_s[L] + bfcf[0];
    outp[b0 + L] = o;
  }
}

extern "C" void kernel_launch(void* const* d_in, const int* in_sizes, int n_in,
                              void* d_out, int out_size, void* d_ws, size_t ws_size,
                              hipStream_t stream) {
  (void)in_sizes; (void)n_in; (void)out_size; (void)ws_size;
  f16* wsA = (f16*)d_ws;            // 16*512*8 = 65536 halves (128 KiB)
  f16* wsH = wsA + 65536;           // 64*512*8 = 262144 halves (512 KiB)
  pack_wa1c<<<32, 256, 0, stream>>>((const float*)d_in[2], wsA);
  pack_whh2<<<128, 256, 0, stream>>>((const float*)d_in[7], wsH);
  decoder_kernel<<<256, 512, 0, stream>>>(
      (const float*)d_in[0], (const float*)d_in[1], (const float*)d_in[2],
      (const float*)d_in[3], (const float*)d_in[4], (const float*)d_in[5],
      (const float*)d_in[6], (const float*)d_in[8], (const float*)d_in[9],
      (const float*)d_in[10], (const float*)d_in[11], (const float*)d_in[12],
      (const float*)d_in[13], wsA, wsH, (float*)d_out);
}

// Round 7
// 1777.173 us; speedup vs baseline: 2.9183x; 1.0271x over previous
//
#include <hip/hip_runtime.h>

typedef _Float16 f16;
typedef _Float16 h2 __attribute__((ext_vector_type(2)));
typedef _Float16 h4 __attribute__((ext_vector_type(4)));
typedef _Float16 h8 __attribute__((ext_vector_type(8)));

#define T127 127

__device__ __forceinline__ float rcp_f(float x) { return __builtin_amdgcn_rcpf(x); }

__device__ __forceinline__ float fdot2(h2 a, h2 b, float c) {
  return __builtin_amdgcn_fdot2(a, b, c, false);
}
__device__ __forceinline__ h2 mk2(f16 a, f16 b) { h2 v; v[0] = a; v[1] = b; return v; }

__device__ __forceinline__ float fast_tanh(float x) {
  x = fminf(fmaxf(x, -12.f), 12.f);
  float e = __expf(2.f * x);
  return (e - 1.f) * rcp_f(e + 1.f);
}
__device__ __forceinline__ float fast_sig(float x) {
  x = fminf(fmaxf(x, -30.f), 30.f);
  return rcp_f(1.f + __expf(-x));
}

// ---- pack Wa1 h+c parts fp32 -> fp16 single u-stream ----
// wsU[(it*512 + L)*8 + j] = Wa1[L>>1][(it>>4)*256 + (L&1)*128 + (it&15)*8 + j]
// it 0..15: h-cols; it 16..31: c-cols. 256 KB.
__global__ void pack_wsU(const float* __restrict__ Wa1, f16* __restrict__ wsU) {
  int tid = blockIdx.x * 256 + threadIdx.x;  // 64 blocks
  int it = tid >> 9, L = tid & 511;
  int kL = L >> 1, g2 = L & 1;
  const float* src = Wa1 + (size_t)kL * 768 + (it >> 4) * 256 + g2 * 128 + (it & 15) * 8;
  f16* dst = wsU + (size_t)tid * 8;
#pragma unroll
  for (int j = 0; j < 8; ++j) dst[j] = (f16)src[j];
}

// ---- pack Whh fp32 -> fp16, gate-major per-cell stream ----
// wsH[((i*4+g)*256 + kk)*8 + j] = Whh[(g*256+kk)*256 + i*8 + j]; i 0..31 col-chunk.
__global__ void pack_wsH(const float* __restrict__ Whh, f16* __restrict__ wsH) {
  int tid = blockIdx.x * 256 + threadIdx.x;  // 128 blocks
  int m = tid >> 8;       // (i*4+g) 0..127
  int kk = tid & 255;
  int i = m >> 2, g = m & 3;
  const float* src = Whh + (size_t)(g * 256 + kk) * 256 + i * 8;
  f16* dst = wsH + (size_t)tid * 8;
#pragma unroll
  for (int j = 0; j < 8; ++j) dst[j] = (f16)src[j];
}

// 256 blocks x 512 threads, 1 block/CU. WG=512 -> 128-VGPR budget (WG=1024 is
// hard-clamped to 64 VGPRs and spills; rounds 2-4. Keep WG=512.)
// Round-7: zero resident weights -> deep prefetch (u-stream 4-deep, Whh 2-deep
// x4 gates); D/E fused via lane remap (bb=L&1,kk=L>>1) -> 3 barriers/step,
// no gact LDS; interleaved softmax reduction chains.
__global__ __attribute__((amdgpu_flat_work_group_size(512, 512)))
void decoder_kernel(
    const float* __restrict__ enc,    // [512][127][256]
    const float* __restrict__ yhist,  // [512][127]
    const float* __restrict__ Wa1,    // [256][768] (prologue only)
    const float* __restrict__ ba1,    // [256]
    const float* __restrict__ Wa2,    // [256]
    const float* __restrict__ ba2,    // [1]
    const float* __restrict__ Wih,    // [1024]
    const float* __restrict__ bih,    // [1024]
    const float* __restrict__ bhh,    // [1024]
    const float* __restrict__ Wfc,    // [257]
    const float* __restrict__ bfc,    // [1]
    const float* __restrict__ Wfcf,   // [512]
    const float* __restrict__ bfcf,   // [1]
    const f16* __restrict__ wsU,      // packed Wa1 h|c [32][512][8]
    const f16* __restrict__ wsH,      // packed Whh [128][256][8]
    float* __restrict__ outp)         // [512] out ++ [512][127][127] weight
{
  __shared__ __align__(16) f16 tE1[2][T127][280];   // tanh(E1), chunks at g*68
  __shared__ __align__(16) f16 hch[2][4][136];      // h (chunks 0,1) | c (2,3) fp16
  __shared__ __align__(16) float s_arr[2][4][68];   // s = tanh(u+b1)
  __shared__ __align__(16) float score_s[2][128];
  __shared__ __align__(16) float p_s[2][128];       // e . Wfc[0:256]
  __shared__ __align__(16) float q_s[2][128];       // e . Wfcf[256:512]
  __shared__ __align__(16) f16 est[8][288];         // prologue staging
  __shared__ __align__(16) float w2_lds[256];
  __shared__ __align__(16) float yh_s[2][128];
  __shared__ float ctxq_s[2], red2[16];

  const int L = threadIdx.x;   // 0..511
  const int b0 = blockIdx.x * 2;
  const int kL = L >> 1;       // u-output index 0..255
  const int g2 = L & 1;        // u col-half selector
  const int kk2 = L >> 1;      // owned LSTM cell
  const int bbE = L & 1;       // owned batch (cell state)
  const int g_u = L & 3;

  // ---------------- init ----------------
  for (int i = L; i < 1088; i += 512) ((f16*)hch)[i] = (f16)0.f;
  if (L < 256) {
    w2_lds[L] = Wa2[L];
    int bb = L >> 7, tt = L & 127;
    if (tt < T127) yh_s[bb][tt] = yhist[(size_t)(b0 + bb) * T127 + tt];
  }
  float c_reg = 0.f;  // fp32 cell state for (bbE, kk2)

  // ---------------- prologue: tE1 = tanh(e.W1e), p, q ----------------
  {
    h2 we1[64];  // W1e[kL][g2*128 .. +128]
    {
      const float4* wrow = (const float4*)(Wa1 + (size_t)kL * 768 + 512 + g2 * 128);
#pragma unroll
      for (int i = 0; i < 32; ++i) {
        float4 w = wrow[i];
        we1[2 * i]     = mk2((f16)w.x, (f16)w.y);
        we1[2 * i + 1] = mk2((f16)w.z, (f16)w.w);
      }
    }
    const int prow = L >> 6;      // wave id = staged row 0..7
    const int lm = L & 63;
    const int sg = lm >> 4;       // staging chunk 0..3 (72-elem stride)
    const int si = (lm * 4) & 63;

#pragma unroll 1
    for (int tt = 0; tt < 32; ++tt) {
      __syncthreads();
      {  // stage 8 (b,j) rows as fp16: row = bbs*4 + j4, j = tt*4+j4
        int bbs = prow >> 2, j4 = prow & 3, j = tt * 4 + j4;
        float4 v = make_float4(0.f, 0.f, 0.f, 0.f);
        if (j < T127)
          v = *(const float4*)(enc + (((size_t)(b0 + bbs)) * T127 + j) * 256 + lm * 4);
        h4 hv; hv[0] = (f16)v.x; hv[1] = (f16)v.y; hv[2] = (f16)v.z; hv[3] = (f16)v.w;
        *(h4*)(&est[prow][0] + sg * 72 + si) = hv;
      }
      __syncthreads();
#pragma unroll 1
      for (int P = 0; P < 8; ++P) {
        int bbs = P >> 2, j4 = P & 3, j = tt * 4 + j4;
        const h8* ep = (const h8*)(&est[P][0] + (2 * g2) * 72);
        const h8* ep2 = (const h8*)(&est[P][0] + (2 * g2 + 1) * 72);
        float a0 = 0.f, a1 = 0.f;
#pragma unroll
        for (int r = 0; r < 8; ++r) {
          h8 e8 = ep[r];
          a0 = fdot2(we1[4 * r + 0], mk2(e8[0], e8[1]), a0);
          a1 = fdot2(we1[4 * r + 1], mk2(e8[2], e8[3]), a1);
          a0 = fdot2(we1[4 * r + 2], mk2(e8[4], e8[5]), a0);
          a1 = fdot2(we1[4 * r + 3], mk2(e8[6], e8[7]), a1);
        }
#pragma unroll
        for (int r = 0; r < 8; ++r) {
          h8 e8 = ep2[r];
          a0 = fdot2(we1[32 + 4 * r + 0], mk2(e8[0], e8[1]), a0);
          a1 = fdot2(we1[32 + 4 * r + 1], mk2(e8[2], e8[3]), a1);
          a0 = fdot2(we1[32 + 4 * r + 2], mk2(e8[4], e8[5]), a0);
          a1 = fdot2(we1[32 + 4 * r + 3], mk2(e8[6], e8[7]), a1);
        }
        float acc = a0 + a1;
        acc += __shfl_xor(acc, 1, 64);
        if (g2 == 0 && j < T127)
          tE1[bbs][j][(kL >> 6) * 68 + (kL & 63)] = (f16)fast_tanh(acc);
      }
      {  // p, q for this wave's staged row
        int bbs = prow >> 2, j4 = prow & 3, j = tt * 4 + j4;
        float4 wp4 = *(const float4*)(Wfc + lm * 4);
        float4 wq4 = *(const float4*)(Wfcf + 256 + lm * 4);
        h4 ev = *(const h4*)(&est[prow][0] + sg * 72 + si);
        float pacc = (float)ev[0] * wp4.x + (float)ev[1] * wp4.y + (float)ev[2] * wp4.z + (float)ev[3] * wp4.w;
        float qacc = (float)ev[0] * wq4.x + (float)ev[1] * wq4.y + (float)ev[2] * wq4.z + (float)ev[3] * wq4.w;
#pragma unroll
        for (int s = 32; s; s >>= 1) {
          pacc += __shfl_xor(pacc, s, 64);
          qacc += __shfl_xor(qacc, s, 64);
        }
        if (lm == 0 && j < T127) { p_s[bbs][j] = pacc; q_s[bbs][j] = qacc; }
      }
    }
  }
  __syncthreads();

  // ---------------- persistent per-lane constants ----------------
  const float b1k = ba1[kL];
  const float wih0 = Wih[kk2];            // gate i row
  const float wih1 = Wih[256 + kk2];      // f
  const float wih2 = Wih[512 + kk2];      // g
  const float wih3 = Wih[768 + kk2];      // o
  const float bia0 = bih[kk2] + bhh[kk2];
  const float bia1 = bih[256 + kk2] + bhh[256 + kk2];
  const float bia2 = bih[512 + kk2] + bhh[512 + kk2];
  const float bia3 = bih[768 + kk2] + bhh[768 + kk2];
  const float ba2v = ba2[0];
  const float wfcy = Wfc[256];
  const float bfc0 = bfc[0];
  const float wfcf_k = Wfcf[kk2];
  const f16* hbase = (const f16*)hch + bbE * 544;  // own batch h|c base

  // ---------------- 127 sequential steps ----------------
#pragma unroll 1
  for (int t = 0; t < T127; ++t) {
    const h8* wU = (const h8*)wsU + L;     // u-stream chunk it at wU[it*512]
    const h8* wHp = (const h8*)wsH + kk2;  // gh chunk (i,g) at wHp[(i*4+g)*256]

    // ---- Phase A1: u = Wa1.[h;c], fully streamed, 4-deep prefetch ----
    float u0a = 0.f, u0b = 0.f, u1a = 0.f, u1b = 0.f;
    {
      h8 a0 = wU[0], a1 = wU[512], a2 = wU[1024], a3 = wU[1536];
#pragma unroll 4
      for (int it = 0; it < 32; ++it) {
        h8 nxt = wU[((it + 4) & 31) * 512];
        int ch = (it >> 4) * 2 + g2;           // h: g2 ; c: 2+g2
        const f16* hp = (const f16*)hch + ch * 136 + (it & 15) * 8;
        h8 x = *(const h8*)hp;           // batch 0
        h8 y = *(const h8*)(hp + 544);   // batch 1
        u0a = fdot2(mk2(a0[0], a0[1]), mk2(x[0], x[1]), u0a);
        u0b = fdot2(mk2(a0[2], a0[3]), mk2(x[2], x[3]), u0b);
        u0a = fdot2(mk2(a0[4], a0[5]), mk2(x[4], x[5]), u0a);
        u0b = fdot2(mk2(a0[6], a0[7]), mk2(x[6], x[7]), u0b);
        u1a = fdot2(mk2(a0[0], a0[1]), mk2(y[0], y[1]), u1a);
        u1b = fdot2(mk2(a0[2], a0[3]), mk2(y[2], y[3]), u1b);
        u1a = fdot2(mk2(a0[4], a0[5]), mk2(y[4], y[5]), u1a);
        u1b = fdot2(mk2(a0[6], a0[7]), mk2(y[6], y[7]), u1b);
        a0 = a1; a1 = a2; a2 = a3; a3 = nxt;
      }
    }
    {
      float u0 = u0a + u0b, u1 = u1a + u1b;
      u0 += __shfl_xor(u0, 1, 64);
      u1 += __shfl_xor(u1, 1, 64);
      if (g2 == 0) s_arr[0][kL >> 6][kL & 63] = fast_tanh(u0 + b1k);
      else         s_arr[1][kL >> 6][kL & 63] = fast_tanh(u1 + b1k);
    }
    __syncthreads();  // #1: s_arr visible

    // ---- Fused: Whh stream (2-deep x 4 gates) + gh dots + attn scores ----
    float gh0 = 0.f, gh1 = 0.f, gh2 = 0.f, gh3 = 0.f;
    float acc0 = 0.f, acc1 = 0.f;
    int pr = L >> 2;
    int bbB = pr & 1, jB = pr >> 1;
    const h4* tp = (const h4*)&tE1[bbB][jB][g_u * 68];
    const float4* sp = (const float4*)&s_arr[bbB][g_u][0];
    const float4* w2p = (const float4*)&w2_lds[g_u * 64];
    h8 A0 = wHp[0], A1 = wHp[256], A2 = wHp[512], A3 = wHp[768];
    h8 B0 = wHp[1024], B1 = wHp[1280], B2 = wHp[1536], B3 = wHp[1792];

#define FUSED_BODY(C0, C1, C2, C3, IDX)                                        \
    {                                                                          \
      int ip = ((IDX) + 2) & 31;                                               \
      h8 T0 = wHp[(ip * 4 + 0) * 256], T1 = wHp[(ip * 4 + 1) * 256];           \
      h8 T2 = wHp[(ip * 4 + 2) * 256], T3 = wHp[(ip * 4 + 3) * 256];           \
      h8 x = *(const h8*)(hbase + ((IDX) >> 4) * 136 + ((IDX) & 15) * 8);      \
      gh0 = fdot2(mk2(C0[0], C0[1]), mk2(x[0], x[1]), gh0);                    \
      gh0 = fdot2(mk2(C0[2], C0[3]), mk2(x[2], x[3]), gh0);                    \
      gh0 = fdot2(mk2(C0[4], C0[5]), mk2(x[4], x[5]), gh0);                    \
      gh0 = fdot2(mk2(C0[6], C0[7]), mk2(x[6], x[7]), gh0);                    \
      gh1 = fdot2(mk2(C1[0], C1[1]), mk2(x[0], x[1]), gh1);                    \
      gh1 = fdot2(mk2(C1[2], C1[3]), mk2(x[2], x[3]), gh1);                    \
      gh1 = fdot2(mk2(C1[4], C1[5]), mk2(x[4], x[5]), gh1);                    \
      gh1 = fdot2(mk2(C1[6], C1[7]), mk2(x[6], x[7]), gh1);                    \
      gh2 = fdot2(mk2(C2[0], C2[1]), mk2(x[0], x[1]), gh2);                    \
      gh2 = fdot2(mk2(C2[2], C2[3]), mk2(x[2], x[3]), gh2);                    \
      gh2 = fdot2(mk2(C2[4], C2[5]), mk2(x[4], x[5]), gh2);                    \
      gh2 = fdot2(mk2(C2[6], C2[7]), mk2(x[6], x[7]), gh2);                    \
      gh3 = fdot2(mk2(C3[0], C3[1]), mk2(x[0], x[1]), gh3);                    \
      gh3 = fdot2(mk2(C3[2], C3[3]), mk2(x[2], x[3]), gh3);                    \
      gh3 = fdot2(mk2(C3[4], C3[5]), mk2(x[4], x[5]), gh3);                    \
      gh3 = fdot2(mk2(C3[6], C3[7]), mk2(x[6], x[7]), gh3);                    \
      {                                                                        \
        int ii = (IDX) & 15;                                                   \
        h4 tv = tp[ii];                                                        \
        float4 sv = sp[ii];                                                    \
        float4 wv2 = w2p[ii];                                                  \
        float t0 = (float)tv[0], t1 = (float)tv[1];                            \
        float t2 = (float)tv[2], t3 = (float)tv[3];                            \
        acc0 = fmaf(wv2.x * (sv.x + t0), rcp_f(fmaf(sv.x, t0, 1.f)), acc0);    \
        acc1 = fmaf(wv2.y * (sv.y + t1), rcp_f(fmaf(sv.y, t1, 1.f)), acc1);    \
        acc0 = fmaf(wv2.z * (sv.z + t2), rcp_f(fmaf(sv.z, t2, 1.f)), acc0);    \
        acc1 = fmaf(wv2.w * (sv.w + t3), rcp_f(fmaf(sv.w, t3, 1.f)), acc1);    \
        if (ii == 15) {                                                        \
          float acc = acc0 + acc1;                                             \
          acc += __shfl_xor(acc, 1, 64);                                       \
          acc += __shfl_xor(acc, 2, 64);                                       \
          if (g_u == 0 && pr < 254) score_s[bbB][jB] = acc + ba2v;             \
          acc0 = 0.f; acc1 = 0.f;                                              \
          pr = (L >> 2) + 128;                                                 \
          int prc = (pr < 254) ? pr : 253;                                     \
          bbB = prc & 1; jB = prc >> 1;                                        \
          tp = (const h4*)&tE1[bbB][jB][g_u * 68];                             \
          sp = (const float4*)&s_arr[bbB][g_u][0];                             \
        }                                                                      \
      }                                                                        \
      C0 = T0; C1 = T1; C2 = T2; C3 = T3;                                      \
    }

#pragma unroll 1
    for (int ih = 0; ih < 16; ++ih) {
      int i0 = 2 * ih;
      FUSED_BODY(A0, A1, A2, A3, i0)
      int i1 = 2 * ih + 1;
      FUSED_BODY(B0, B1, B2, B3, i1)
    }
#undef FUSED_BODY
    __syncthreads();  // #2: score_s visible

    // ---- Phase C: redundant per-wave softmax, interleaved reductions ----
    float ytil0, ytil1;
    {
      const int ln = L & 63;
      const int wv = L >> 6;
      float e0a = __expf(score_s[0][ln]);
      float e1a = (ln < 63) ? __expf(score_s[0][64 + ln]) : 0.f;
      float e0b = __expf(score_s[1][ln]);
      float e1b = (ln < 63) ? __expf(score_s[1][64 + ln]) : 0.f;
      float sa = e0a + e1a, sb = e0b + e1b;
      float cwa = e0a * p_s[0][ln] + ((ln < 63) ? e1a * p_s[0][64 + ln] : 0.f);
      float cwb = e0b * p_s[1][ln] + ((ln < 63) ? e1b * p_s[1][64 + ln] : 0.f);
#pragma unroll
      for (int s = 32; s; s >>= 1) {
        sa += __shfl_xor(sa, s, 64);
        sb += __shfl_xor(sb, s, 64);
        cwa += __shfl_xor(cwa, s, 64);
        cwb += __shfl_xor(cwb, s, 64);
      }
      float ra = rcp_f(sa), rb = rcp_f(sb);
      if (wv == 0) {
        float* wout = outp + 512 + ((size_t)b0 * T127 + t) * T127;
        wout[ln] = e0a * ra;
        if (ln < 63) wout[64 + ln] = e1a * ra;
      } else if (wv == 1) {
        float* wout = outp + 512 + ((size_t)(b0 + 1) * T127 + t) * T127;
        wout[ln] = e0b * rb;
        if (ln < 63) wout[64 + ln] = e1b * rb;
      }
      ytil0 = cwa * ra + wfcy * yh_s[0][t] + bfc0;
      ytil1 = cwb * rb + wfcy * yh_s[1][t] + bfc0;
      if (t == T127 - 1) {
        float cqa = e0a * q_s[0][ln] + ((ln < 63) ? e1a * q_s[0][64 + ln] : 0.f);
        float cqb = e0b * q_s[1][ln] + ((ln < 63) ? e1b * q_s[1][64 + ln] : 0.f);
#pragma unroll
        for (int s = 32; s; s >>= 1) {
          cqa += __shfl_xor(cqa, s, 64);
          cqb += __shfl_xor(cqb, s, 64);
        }
        if (L == 0) { ctxq_s[0] = cqa * ra; ctxq_s[1] = cqb * rb; }
      }
    }

    // ---- Phase D+E fused: gates + cell update, all in-lane ----
    {
      float yt = bbE ? ytil1 : ytil0;
      float g_i = gh0 + wih0 * yt + bia0;
      float g_f = gh1 + wih1 * yt + bia1;
      float g_g = gh2 + wih2 * yt + bia2;
      float g_o = gh3 + wih3 * yt + bia3;
      float ai = fast_sig(g_i);
      float af = fast_sig(g_f);
      float ag = fast_tanh(g_g);
      float ao = fast_sig(g_o);
      float cn = af * c_reg + ai * ag;
      float hn = ao * fast_tanh(cn);
      c_reg = cn;
      hch[bbE][kk2 >> 7][kk2 & 127] = (f16)hn;
      hch[bbE][2 + (kk2 >> 7)][kk2 & 127] = (f16)cn;
      if (t == T127 - 1) {
        float po = wfcf_k * hn;
        po += __shfl_xor(po, 32, 64);
        po += __shfl_xor(po, 16, 64);
        po += __shfl_xor(po, 8, 64);
        po += __shfl_xor(po, 4, 64);
        po += __shfl_xor(po, 2, 64);
        if ((L & 63) < 2) red2[(L >> 6) * 2 + (L & 1)] = po;
      }
    }
    __syncthreads();  // #3: hch (+ red2/ctxq on last step) visible
  }

  // ---------------- final: out = Wfcf[0:256].h + ctx.Wfcf[256:512] + b ----------------
  if (L < 2) {
    float o = ctxq_s[L] + bfcf[0];
#pragma unroll
    for (int w = 0; w < 8; ++w) o += red2[w * 2 + L];
    outp[b0 + L] = o;
  }
}

extern "C" void kernel_launch(void* const* d_in, const int* in_sizes, int n_in,
                              void* d_out, int out_size, void* d_ws, size_t ws_size,
                              hipStream_t stream) {
  (void)in_sizes; (void)n_in; (void)out_size; (void)ws_size;
  f16* wsU = (f16*)d_ws;            // 32*512*8 = 131072 halves (256 KiB)
  f16* wsH = wsU + 131072;          // 128*256*8 = 262144 halves (512 KiB)
  pack_wsU<<<64, 256, 0, stream>>>((const float*)d_in[2], wsU);
  pack_wsH<<<128, 256, 0, stream>>>((const float*)d_in[7], wsH);
  decoder_kernel<<<256, 512, 0, stream>>>(
      (const float*)d_in[0], (const float*)d_in[1], (const float*)d_in[2],
      (const float*)d_in[3], (const float*)d_in[4], (const float*)d_in[5],
      (const float*)d_in[6], (const float*)d_in[8], (const float*)d_in[9],
      (const float*)d_in[10], (const float*)d_in[11], (const float*)d_in[12],
      (const float*)d_in[13], wsU, wsH, (float*)d_out);
}